// Round 17
// baseline (288.579 us; speedup 1.0000x reference)
//
#include <hip/hip_runtime.h>

#define N_NODES 200000
#define N_EDGES 1250000
#define N_RELS 8
#define NROWS 1600000        // N_NODES * N_RELS
#define NROWS_PAD 1601536    // 782 * 2048
#define NSCAN 782
#define NBUCK 6250           // N_NODES / 32

#define NB_COUNT 4883        // ceil(N_EDGES/256)
#define NB_XCAST 6250        // 1.6M/256
#define NB_PREP1 144         // 64*576/256
#define NB_PREP2 72          // 32*576/256

typedef __attribute__((ext_vector_type(8))) short short8v;
typedef __attribute__((ext_vector_type(4))) float f32x4;

__device__ __forceinline__ ushort rne_bf16(float v) {
  unsigned u = __float_as_uint(v);
  return (ushort)((u + 0x7FFFu + ((u >> 16) & 1u)) >> 16);
}

// ---------------- fused setup: count(+rank) | xcast | prep1 | prep2 ----------------

__device__ __forceinline__ void prep_body(const float* W, const float* Root,
                                          ushort* Bf, int ncol, int i) {
  int col = i / 576, k = i - col * 576;
  float w = (k < 512) ? W[k * ncol + col] : Root[(k - 512) * ncol + col];
  int WN = ncol >> 4;
  int ks = k >> 5, kg = (k >> 3) & 3, j = k & 7;
  int wn = col >> 4, l15 = col & 15;
  int lane = (kg << 4) | l15;
  Bf[(ks * WN + wn) * 512 + lane * 8 + j] = rne_bf16(w);
}

__global__ __launch_bounds__(256) void k_setup(
    const int* __restrict__ ei, const int* __restrict__ et, int* __restrict__ cnt,
    int* __restrict__ er,
    const float* __restrict__ x, ushort* __restrict__ xbf,
    const float* __restrict__ w1, const float* __restrict__ r1, ushort* __restrict__ bf1,
    const float* __restrict__ w2, const float* __restrict__ r2, ushort* __restrict__ bf2) {
  int blk = blockIdx.x, t = threadIdx.x;
  if (blk < NB_COUNT) {
    int e = blk * 256 + t;
    if (e < N_EDGES) {
      int dst = ei[N_EDGES + e];
      int r = et[e];
      er[e] = atomicAdd(&cnt[dst * N_RELS + r], 1);   // rank within (dst,rel)
    }
  } else if (blk < NB_COUNT + NB_XCAST) {
    int i = (blk - NB_COUNT) * 256 + t;   // i < 1.6M
    float4 a = ((const float4*)x)[i * 2];
    float4 b = ((const float4*)x)[i * 2 + 1];
    union { uint4 q; ushort u[8]; } o;
    o.u[0] = rne_bf16(a.x); o.u[1] = rne_bf16(a.y);
    o.u[2] = rne_bf16(a.z); o.u[3] = rne_bf16(a.w);
    o.u[4] = rne_bf16(b.x); o.u[5] = rne_bf16(b.y);
    o.u[6] = rne_bf16(b.z); o.u[7] = rne_bf16(b.w);
    ((uint4*)xbf)[i] = o.q;
  } else if (blk < NB_COUNT + NB_XCAST + NB_PREP1) {
    int i = (blk - NB_COUNT - NB_XCAST) * 256 + t;
    prep_body(w1, r1, bf1, 64, i);
  } else {
    int i = (blk - NB_COUNT - NB_XCAST - NB_PREP1) * 256 + t;
    prep_body(w2, r2, bf2, 32, i);
  }
}

// ---------------- sort infrastructure ----------------

__global__ __launch_bounds__(256) void k_bsum(const int* __restrict__ cnt,
                                              int* __restrict__ bsum) {
  __shared__ int sh[256];
  int b = blockIdx.x, t = threadIdx.x;
  const int4* p = (const int4*)(cnt + b * 2048);
  int4 v0 = p[2 * t], v1 = p[2 * t + 1];
  int s = v0.x + v0.y + v0.z + v0.w + v1.x + v1.y + v1.z + v1.w;
  sh[t] = s;
  __syncthreads();
  for (int o = 128; o >= 1; o >>= 1) {
    if (t < o) sh[t] += sh[t + o];
    __syncthreads();
  }
  if (t == 0) bsum[b] = sh[0];
}

__global__ __launch_bounds__(1024) void k_scan1(const int* __restrict__ bsum,
                                                int* __restrict__ bpre,
                                                int* __restrict__ rowoff) {
  __shared__ int sh[1024];
  int t = threadIdx.x;
  int v = (t < NSCAN) ? bsum[t] : 0;
  sh[t] = v;
  __syncthreads();
  for (int o = 1; o < 1024; o <<= 1) {
    int a = (t >= o) ? sh[t - o] : 0;
    __syncthreads();
    sh[t] += a;
    __syncthreads();
  }
  if (t < NSCAN) bpre[t] = sh[t] - v;
  if (t == 0) rowoff[NROWS] = N_EDGES;
}

__global__ __launch_bounds__(256) void k_apply(const int* __restrict__ cnt,
                                               const int* __restrict__ bpre,
                                               int* __restrict__ rowoff) {
  __shared__ int sh[256];
  int b = blockIdx.x, t = threadIdx.x;
  const int4* p = (const int4*)(cnt + b * 2048);
  int4 v0 = p[2 * t], v1 = p[2 * t + 1];
  int v[8] = {v0.x, v0.y, v0.z, v0.w, v1.x, v1.y, v1.z, v1.w};
  int s = 0;
#pragma unroll
  for (int j = 0; j < 8; ++j) s += v[j];
  sh[t] = s;
  __syncthreads();
  for (int o = 1; o < 256; o <<= 1) {
    int a = (t >= o) ? sh[t - o] : 0;
    __syncthreads();
    sh[t] += a;
    __syncthreads();
  }
  int run = bpre[b] + sh[t] - s;
  int base = b * 2048 + t * 8;
#pragma unroll
  for (int j = 0; j < 8; ++j) {
    int i = base + j;
    if (i < NROWS) rowoff[i] = run;
    run += v[j];
  }
}

// place edges sorted by row = dst*8+rel (no atomics: pos = rowoff + rank)
__global__ void k_scatter(const int* __restrict__ ei, const int* __restrict__ et,
                          const int* __restrict__ rowoff, const int* __restrict__ er,
                          int* __restrict__ ep) {
  int e = blockIdx.x * 256 + threadIdx.x;
  if (e < N_EDGES) {
    int src = ei[e];
    int dst = ei[N_EDGES + e];
    int r = et[e];
    int row = dst * N_RELS + r;
    int pos = rowoff[row] + er[e];
    ep[pos] = src | ((row & 255) << 18);
  }
}

// ---------------- fused aggregate + MFMA transform ----------------
// Block: 32 dsts = 256 rows, 512 threads (8 waves), ~34 KB LDS -> 4 blk/CU.
// Wave partition: threads t<9 binary-search loff[0..256] so each wave's
// contiguous row range holds ~n/8 edges.
// Phase 1 (batch-16 x depth-2 = 32 edges in flight): issue-to-consume
// distance ~16 edges (~320+ cyc of work) finally covers the ~400-cyc
// L2-miss gather latency (FETCH 122 B/edge: 85% of gathers L3-served).
// Fast path handles only FULL batches (n & ~15): no index clamps, no
// consume guards. Payload superblocks (64 edges) via v_readlane,
// prefetched one ahead. Scalar tail. Flush: mean -> round-half-up bf16 ->
// one ds_write_b16 into the swizzled plane.
// Phase 2 (NCOL=64): 8 waves = 2M x 4N, full K=576/wave; LDS-staged
// coalesced uint2 epilogue. (NCOL=32): 2M x 2N x 2K-split, 2-way LDS reduce.

template <int NCOL, bool RELUOUT, bool OUTBF>
__global__ __launch_bounds__(512, 8) void k_rgcn(
    const ushort* __restrict__ Xg, const ushort* __restrict__ Bf,
    const float* __restrict__ Bias, const int* __restrict__ rowoff,
    const int* __restrict__ ep, void* __restrict__ OutP) {
  __shared__ __align__(16) ushort agg[256 * 64];    // 32 KB bf16 plane
  __shared__ int loff[260];
  __shared__ int wsplit[12];
  __shared__ __align__(16) float bias_lds[64];

  int t = threadIdx.x;
  int b = blockIdx.x;
  int d0 = b * 32;
  int lane = t & 63, w = t >> 6;

  {
    uint4 zz = make_uint4(0, 0, 0, 0);
    uint4* a4 = (uint4*)agg;
#pragma unroll
    for (int q = 0; q < 4; ++q) a4[t + q * 512] = zz;
  }
  if (t < 257) loff[t] = rowoff[b * 256 + t];
  if (t < NCOL) bias_lds[t] = Bias[t];
  __syncthreads();
  if (t < 9) {
    int s0 = loff[0], ntot = loff[256] - s0;
    int target = s0 + ((ntot * t) >> 3);
    int lo = 0, hi = 256;
    while (lo < hi) {
      int mid = (lo + hi) >> 1;
      if (loff[mid] < target) lo = mid + 1; else hi = mid;
    }
    wsplit[t] = lo;
  }
  __syncthreads();

  // ---- phase 1: batch-16 depth-2 pipelined scalar edge stream ----
  {
    int s = __builtin_amdgcn_readfirstlane(loff[wsplit[w]]);
    int e = __builtin_amdgcn_readfirstlane(loff[wsplit[w + 1]]);
    int n = e - s;
    const int* wep = ep + s;
    const char* Xb = (const char*)Xg;
    unsigned lane2 = (unsigned)(lane << 1);
    int cur = -1, nrun = 0;
    float a = 0.f;

#define FLUSH()                                                         \
    {                                                                   \
      float m = a * __builtin_amdgcn_rcpf((float)nrun);                 \
      int sw = (cur << 6) + (lane ^ (((cur >> 3) & 7) << 3));           \
      agg[sw] = (ushort)((__float_as_uint(m) + 0x8000u) >> 16);         \
    }
// full batch of 16: no clamps, no guards (only called within n & ~15)
#define LOADP16(PAY, BASE, PK, HV)                                      \
    {                                                                   \
      _Pragma("unroll")                                                 \
      for (int u = 0; u < 16; ++u) {                                    \
        PK[u] = __builtin_amdgcn_readlane(PAY, (BASE) + u);             \
        HV[u] = *(const ushort*)(Xb + ((((unsigned)PK[u] & 0x3FFFFu) << 7) + lane2)); \
      }                                                                 \
    }
#define CONSUME16(PK, HV)                                               \
    {                                                                   \
      _Pragma("unroll")                                                 \
      for (int u = 0; u < 16; ++u) {                                    \
        int row = (int)((unsigned)PK[u] >> 18);                         \
        float v = __uint_as_float((unsigned)HV[u] << 16);               \
        if (row != cur) {                                               \
          if (cur >= 0) FLUSH();                                        \
          cur = row; a = 0.f; nrun = 0;                                 \
        }                                                               \
        a += v; ++nrun;                                                 \
      }                                                                 \
    }

    if (n > 0) {
      int nfull = n & ~15;
      if (nfull > 0) {
        // superblock 0 payload (clamped coalesced load)
        int pl0 = lane; if (pl0 > n - 1) pl0 = n - 1;
        int payA = wep[pl0];
        for (int base = 0; base < nfull; base += 64) {
          int lim = nfull - base; if (lim > 64) lim = 64;  // multiple of 16
          int nxt = base + 64;
          int payB = payA;
          if (nxt < n) {   // prefetch next superblock payload early
            int pl = nxt + lane; if (pl > n - 1) pl = n - 1;
            payB = wep[pl];
          }
          int nb = lim >> 4;   // 1..4 full batches
          {
            int pk0[16], pk1[16];
            ushort hv0[16], hv1[16];
            LOADP16(payA, 0, pk0, hv0);
            int k = 0;
            while (true) {
              if (k + 1 < nb) LOADP16(payA, (k + 1) << 4, pk1, hv1);
              CONSUME16(pk0, hv0);
              ++k; if (k >= nb) break;
              if (k + 1 < nb) LOADP16(payA, (k + 1) << 4, pk0, hv0);
              CONSUME16(pk1, hv1);
              ++k; if (k >= nb) break;
            }
          }
          payA = payB;
        }
      }
      // scalar tail (<= 15 edges)
      for (int i = nfull; i < n; ++i) {
        int pk = __builtin_amdgcn_readfirstlane(wep[i]);
        ushort hv = *(const ushort*)(Xb + ((((unsigned)pk & 0x3FFFFu) << 7) + lane2));
        int row = (int)((unsigned)pk >> 18);
        float v = __uint_as_float((unsigned)hv << 16);
        if (row != cur) {
          if (cur >= 0) FLUSH();
          cur = row; a = 0.f; nrun = 0;
        }
        a += v; ++nrun;
      }
      if (cur >= 0) FLUSH();
    }
#undef CONSUME16
#undef LOADP16
#undef FLUSH
  }
  __syncthreads();

  // ---- phase 2: pure-bf16 MFMA ----
  int l15 = lane & 15, kg = lane >> 4;
  f32x4 acc = {0.f, 0.f, 0.f, 0.f};

  if constexpr (NCOL == 64) {
    int wm = w >> 2, wn = w & 3;
    int col = wn * 16 + l15;
    for (int ks = 0; ks < 18; ++ks) {
      union { uint4 q; short8v s; } bh, ah;
      bh.q = *(const uint4*)(Bf + (ks * 4 + wn) * 512 + lane * 8);
      if (ks < 16) {
        int rr = ks >> 1;
        int f0 = ((ks & 1) << 5) + (kg << 3);
        int row = ((wm * 16 + l15) << 3) + rr;
        int sw = (row << 6) + (f0 ^ ((l15 & 7) << 3));
        ah.q = *(const uint4*)&agg[sw];
      } else {
        int kb = ((ks - 16) << 5) + (kg << 3);
        ah.q = *(const uint4*)&Xg[(size_t)(d0 + wm * 16 + l15) * 64 + kb];
      }
      acc = __builtin_amdgcn_mfma_f32_16x16x32_bf16(ah.s, bh.s, acc, 0, 0, 0);
    }
    // epilogue: LDS-staged coalesced stores
    __syncthreads();                 // all agg reads done; reuse as stage
#pragma unroll
    for (int i2 = 0; i2 < 4; ++i2) {
      float v = acc[i2] + bias_lds[col];
      if (RELUOUT) v = fmaxf(v, 0.f);
      agg[(wm * 16 + kg * 4 + i2) * 64 + col] = rne_bf16(v);
    }
    __syncthreads();
    {
      int r = t >> 4, c4 = t & 15;
      uint2 v = *(const uint2*)&agg[r * 64 + c4 * 4];
      ((uint2*)OutP)[(size_t)(d0 + r) * 16 + c4] = v;
    }
  } else {
    int wm = w >> 2, wn = (w >> 1) & 1, ksp = w & 1;
    int col = wn * 16 + l15;
    for (int ks = ksp; ks < 18; ks += 2) {
      union { uint4 q; short8v s; } bh, ah;
      bh.q = *(const uint4*)(Bf + (ks * 2 + wn) * 512 + lane * 8);
      if (ks < 16) {
        int rr = ks >> 1;
        int f0 = ((ks & 1) << 5) + (kg << 3);
        int row = ((wm * 16 + l15) << 3) + rr;
        int sw = (row << 6) + (f0 ^ ((l15 & 7) << 3));
        ah.q = *(const uint4*)&agg[sw];
      } else {
        int kb = ((ks - 16) << 5) + (kg << 3);
        ah.q = *(const uint4*)&Xg[(size_t)(d0 + wm * 16 + l15) * 64 + kb];
      }
      acc = __builtin_amdgcn_mfma_f32_16x16x32_bf16(ah.s, bh.s, acc, 0, 0, 0);
    }
    __syncthreads();               // agg reads done before reuse
    float* red = (float*)agg;
    int rbase = wm * 16 + kg * 4;
    if (ksp == 1) {
#pragma unroll
      for (int i2 = 0; i2 < 4; ++i2) red[(rbase + i2) * 36 + col] = acc[i2];
    }
    __syncthreads();
    if (ksp == 0) {
#pragma unroll
      for (int i2 = 0; i2 < 4; ++i2) {
        float v = acc[i2] + red[(rbase + i2) * 36 + col] + bias_lds[col];
        if (RELUOUT) v = fmaxf(v, 0.f);
        ((float*)OutP)[(size_t)(d0 + rbase + i2) * 32 + col] = v;
      }
    }
  }
}

// ---------------- launch ----------------

extern "C" void kernel_launch(void* const* d_in, const int* in_sizes, int n_in,
                              void* d_out, int out_size, void* d_ws, size_t ws_size,
                              hipStream_t stream) {
  const float* x = (const float*)d_in[0];
  const int* ei = (const int*)d_in[1];
  const int* et = (const int*)d_in[2];
  const float* w1 = (const float*)d_in[3];
  const float* r1 = (const float*)d_in[4];
  const float* b1 = (const float*)d_in[5];
  const float* w2 = (const float*)d_in[6];
  const float* r2 = (const float*)d_in[7];
  const float* b2 = (const float*)d_in[8];
  float* out = (float*)d_out;

  int* cnt = (int*)d_ws;                     // NROWS_PAD ints
  int* bsum = cnt + NROWS_PAD;               // 1024
  int* bpre = bsum + 1024;                   // 1024
  int* rowoff = bpre + 1024;                 // NROWS+1 (pad 16)
  int* er = rowoff + NROWS + 16;             // N_EDGES (edge rank)
  int* ep = er + N_EDGES;                    // N_EDGES
  ushort* bf1 = (ushort*)(ep + N_EDGES);     // 36864 (single plane)
  ushort* bf2 = bf1 + 36864;                 // 18432
  ushort* xbf = bf2 + 18432;                 // 12,800,000 (25.6 MB)
  ushort* hbf = xbf + 12800000;              // 12,800,000 (25.6 MB)

  hipMemsetAsync(cnt, 0, (size_t)NROWS_PAD * 4, stream);
  k_setup<<<NB_COUNT + NB_XCAST + NB_PREP1 + NB_PREP2, 256, 0, stream>>>(
      ei, et, cnt, er, x, xbf, w1, r1, bf1, w2, r2, bf2);
  k_bsum<<<NSCAN, 256, 0, stream>>>(cnt, bsum);
  k_scan1<<<1, 1024, 0, stream>>>(bsum, bpre, rowoff);
  k_apply<<<NSCAN, 256, 0, stream>>>(cnt, bpre, rowoff);
  k_scatter<<<(N_EDGES + 255) / 256, 256, 0, stream>>>(ei, et, rowoff, er, ep);

  k_rgcn<64, true, true><<<NBUCK, 512, 0, stream>>>(xbf, bf1, b1, rowoff, ep, hbf);
  k_rgcn<32, false, false><<<NBUCK, 512, 0, stream>>>(hbf, bf2, b2, rowoff, ep, out);
}

// Round 18
// 279.000 us; speedup vs baseline: 1.0343x; 1.0343x over previous
//
#include <hip/hip_runtime.h>

#define N_NODES 200000
#define N_EDGES 1250000
#define N_RELS 8
#define NROWS 1600000        // N_NODES * N_RELS
#define NROWS_PAD 1601536    // 782 * 2048
#define NSCAN 782
#define NBUCK 6250           // N_NODES / 32

#define NB_COUNT 4883        // ceil(N_EDGES/256)
#define NB_XCAST 6250        // 1.6M/256
#define NB_PREP1 144         // 64*576/256
#define NB_PREP2 72          // 32*576/256

typedef __attribute__((ext_vector_type(8))) short short8v;
typedef __attribute__((ext_vector_type(4))) float f32x4;

__device__ __forceinline__ ushort rne_bf16(float v) {
  unsigned u = __float_as_uint(v);
  return (ushort)((u + 0x7FFFu + ((u >> 16) & 1u)) >> 16);
}

// ---------------- fused setup: count(+rank) | xcast | prep1 | prep2 ----------------

__device__ __forceinline__ void prep_body(const float* W, const float* Root,
                                          ushort* Bf, int ncol, int i) {
  int col = i / 576, k = i - col * 576;
  float w = (k < 512) ? W[k * ncol + col] : Root[(k - 512) * ncol + col];
  int WN = ncol >> 4;
  int ks = k >> 5, kg = (k >> 3) & 3, j = k & 7;
  int wn = col >> 4, l15 = col & 15;
  int lane = (kg << 4) | l15;
  Bf[(ks * WN + wn) * 512 + lane * 8 + j] = rne_bf16(w);
}

__global__ __launch_bounds__(256) void k_setup(
    const int* __restrict__ ei, const int* __restrict__ et, int* __restrict__ cnt,
    int* __restrict__ er,
    const float* __restrict__ x, ushort* __restrict__ xbf,
    const float* __restrict__ w1, const float* __restrict__ r1, ushort* __restrict__ bf1,
    const float* __restrict__ w2, const float* __restrict__ r2, ushort* __restrict__ bf2) {
  int blk = blockIdx.x, t = threadIdx.x;
  if (blk < NB_COUNT) {
    int e = blk * 256 + t;
    if (e < N_EDGES) {
      int dst = ei[N_EDGES + e];
      int r = et[e];
      er[e] = atomicAdd(&cnt[dst * N_RELS + r], 1);   // rank within (dst,rel)
    }
  } else if (blk < NB_COUNT + NB_XCAST) {
    int i = (blk - NB_COUNT) * 256 + t;   // i < 1.6M
    float4 a = ((const float4*)x)[i * 2];
    float4 b = ((const float4*)x)[i * 2 + 1];
    union { uint4 q; ushort u[8]; } o;
    o.u[0] = rne_bf16(a.x); o.u[1] = rne_bf16(a.y);
    o.u[2] = rne_bf16(a.z); o.u[3] = rne_bf16(a.w);
    o.u[4] = rne_bf16(b.x); o.u[5] = rne_bf16(b.y);
    o.u[6] = rne_bf16(b.z); o.u[7] = rne_bf16(b.w);
    ((uint4*)xbf)[i] = o.q;
  } else if (blk < NB_COUNT + NB_XCAST + NB_PREP1) {
    int i = (blk - NB_COUNT - NB_XCAST) * 256 + t;
    prep_body(w1, r1, bf1, 64, i);
  } else {
    int i = (blk - NB_COUNT - NB_XCAST - NB_PREP1) * 256 + t;
    prep_body(w2, r2, bf2, 32, i);
  }
}

// ---------------- sort infrastructure ----------------

__global__ __launch_bounds__(256) void k_bsum(const int* __restrict__ cnt,
                                              int* __restrict__ bsum) {
  __shared__ int sh[256];
  int b = blockIdx.x, t = threadIdx.x;
  const int4* p = (const int4*)(cnt + b * 2048);
  int4 v0 = p[2 * t], v1 = p[2 * t + 1];
  int s = v0.x + v0.y + v0.z + v0.w + v1.x + v1.y + v1.z + v1.w;
  sh[t] = s;
  __syncthreads();
  for (int o = 128; o >= 1; o >>= 1) {
    if (t < o) sh[t] += sh[t + o];
    __syncthreads();
  }
  if (t == 0) bsum[b] = sh[0];
}

__global__ __launch_bounds__(1024) void k_scan1(const int* __restrict__ bsum,
                                                int* __restrict__ bpre,
                                                int* __restrict__ rowoff) {
  __shared__ int sh[1024];
  int t = threadIdx.x;
  int v = (t < NSCAN) ? bsum[t] : 0;
  sh[t] = v;
  __syncthreads();
  for (int o = 1; o < 1024; o <<= 1) {
    int a = (t >= o) ? sh[t - o] : 0;
    __syncthreads();
    sh[t] += a;
    __syncthreads();
  }
  if (t < NSCAN) bpre[t] = sh[t] - v;
  if (t == 0) rowoff[NROWS] = N_EDGES;
}

__global__ __launch_bounds__(256) void k_apply(const int* __restrict__ cnt,
                                               const int* __restrict__ bpre,
                                               int* __restrict__ rowoff) {
  __shared__ int sh[256];
  int b = blockIdx.x, t = threadIdx.x;
  const int4* p = (const int4*)(cnt + b * 2048);
  int4 v0 = p[2 * t], v1 = p[2 * t + 1];
  int v[8] = {v0.x, v0.y, v0.z, v0.w, v1.x, v1.y, v1.z, v1.w};
  int s = 0;
#pragma unroll
  for (int j = 0; j < 8; ++j) s += v[j];
  sh[t] = s;
  __syncthreads();
  for (int o = 1; o < 256; o <<= 1) {
    int a = (t >= o) ? sh[t - o] : 0;
    __syncthreads();
    sh[t] += a;
    __syncthreads();
  }
  int run = bpre[b] + sh[t] - s;
  int base = b * 2048 + t * 8;
#pragma unroll
  for (int j = 0; j < 8; ++j) {
    int i = base + j;
    if (i < NROWS) rowoff[i] = run;
    run += v[j];
  }
}

// place edges sorted by row = dst*8+rel (no atomics: pos = rowoff + rank)
__global__ void k_scatter(const int* __restrict__ ei, const int* __restrict__ et,
                          const int* __restrict__ rowoff, const int* __restrict__ er,
                          int* __restrict__ ep) {
  int e = blockIdx.x * 256 + threadIdx.x;
  if (e < N_EDGES) {
    int src = ei[e];
    int dst = ei[N_EDGES + e];
    int r = et[e];
    int row = dst * N_RELS + r;
    int pos = rowoff[row] + er[e];
    ep[pos] = src | ((row & 255) << 18);
  }
}

// ---------------- fused aggregate + MFMA transform ----------------
// Block: 32 dsts = 256 rows, 512 threads (8 waves). 32 quarter-wave GROUPS
// (4 per wave, 16 lanes each): threads t<33 binary-search loff[0..256] so
// each group gets a contiguous, row-aligned, edge-balanced slice.
// Phase 1: group gathers its edge's x row as uint2 (16 lanes x 8B = 128B,
// 4 features/lane) -> ONE VMEM instruction covers 4 edges per wave step.
// 16-step windows (64 edges in flight/wave); payload superblock in regs,
// distributed by __shfl; group-predicated run-break; flush: mean ->
// round-half-up bf16 x4 -> ds_write_b64 with the same 16B-block XOR swizzle
// phase 2 reads. launch_bounds(512,6): ~84 VGPR so the window stays live
// (the 64-VGPR wall at (512,8) silently serialized r13-r17's pipelines).
// Phase 2 (NCOL=64): 8 waves = 2M x 4N, full K=576/wave; LDS-staged
// coalesced uint2 epilogue. (NCOL=32): 2M x 2N x 2K-split, 2-way LDS reduce.

template <int NCOL, bool RELUOUT, bool OUTBF>
__global__ __launch_bounds__(512, 6) void k_rgcn(
    const ushort* __restrict__ Xg, const ushort* __restrict__ Bf,
    const float* __restrict__ Bias, const int* __restrict__ rowoff,
    const int* __restrict__ ep, void* __restrict__ OutP) {
  __shared__ __align__(16) ushort agg[256 * 64];    // 32 KB bf16 plane
  __shared__ int loff[260];
  __shared__ int wsplit[36];
  __shared__ __align__(16) float bias_lds[64];

  int t = threadIdx.x;
  int b = blockIdx.x;
  int d0 = b * 32;
  int lane = t & 63, w = t >> 6;

  {
    uint4 zz = make_uint4(0, 0, 0, 0);
    uint4* a4 = (uint4*)agg;
#pragma unroll
    for (int q = 0; q < 4; ++q) a4[t + q * 512] = zz;
  }
  if (t < 257) loff[t] = rowoff[b * 256 + t];
  if (t < NCOL) bias_lds[t] = Bias[t];
  __syncthreads();
  if (t < 33) {
    int s0 = loff[0], ntot = loff[256] - s0;
    int target = s0 + (int)(((long long)ntot * t) >> 5);
    int lo = 0, hi = 256;
    while (lo < hi) {
      int mid = (lo + hi) >> 1;
      if (loff[mid] < target) lo = mid + 1; else hi = mid;
    }
    wsplit[t] = lo;
  }
  __syncthreads();

  // ---- phase 1: 4-group quarter-wave gather, 16-step windows ----
  {
    int g = lane >> 4;               // group within wave
    int q = lane & 15;               // lane within group
    int rlo = wsplit[(w << 2) + g];
    int rhi = wsplit[(w << 2) + g + 1];
    int gs = loff[rlo];
    int ge = loff[rhi];
    int n = ge - gs;                 // uniform within group
    // wave-level max group length
    int nm = n;
    { int s2 = __shfl_xor(nm, 16); nm = nm > s2 ? nm : s2;
      s2 = __shfl_xor(nm, 32); nm = nm > s2 ? nm : s2; }
    int nmax = nm;

    const char* Xb = (const char*)Xg;
    unsigned qoff = (unsigned)(q << 3);
    float a0 = 0.f, a1 = 0.f, a2 = 0.f, a3 = 0.f, nrunf = 0.f;
    int cur = -1;

#define FLUSH4()                                                              \
    {                                                                         \
      float r_ = __builtin_amdgcn_rcpf(nrunf);                                \
      float m0 = a0 * r_, m1 = a1 * r_, m2 = a2 * r_, m3 = a3 * r_;           \
      unsigned p0 = ((__float_as_uint(m1) + 0x8000u) & 0xFFFF0000u) |         \
                    ((__float_as_uint(m0) + 0x8000u) >> 16);                  \
      unsigned p1 = ((__float_as_uint(m3) + 0x8000u) & 0xFFFF0000u) |         \
                    ((__float_as_uint(m2) + 0x8000u) >> 16);                  \
      int us = (cur << 6) + ((((q >> 1) ^ ((cur >> 3) & 7)) << 3) |           \
                             ((q & 1) << 2));                                 \
      *(uint2*)&agg[us] = make_uint2(p0, p1);                                 \
    }

    int pi = gs + q;
    if (pi > ge - 1) pi = ge - 1;
    if (pi < 0) pi = 0;
    int pay = ep[pi];

    for (int base = 0; base < nmax; base += 16) {
      int pk[16]; uint2 hv[16];
#pragma unroll
      for (int u = 0; u < 16; ++u) {
        pk[u] = __shfl(pay, (g << 4) | u);
        hv[u] = *(const uint2*)(Xb + ((((unsigned)pk[u] & 0x3FFFFu) << 7) + qoff));
      }
      {  // prefetch next window's payload superblock
        int nb2 = base + 16;
        if (nb2 < nmax) {
          int p2 = gs + nb2 + q;
          if (p2 > ge - 1) p2 = ge - 1;
          if (p2 < 0) p2 = 0;
          pay = ep[p2];
        }
      }
#pragma unroll
      for (int u = 0; u < 16; ++u) {
        bool active = (base + u) < n;
        int row = (int)((unsigned)pk[u] >> 18);
        unsigned x0 = hv[u].x, x1 = hv[u].y;
        float v0 = __uint_as_float(x0 << 16);
        float v1 = __uint_as_float(x0 & 0xFFFF0000u);
        float v2 = __uint_as_float(x1 << 16);
        float v3 = __uint_as_float(x1 & 0xFFFF0000u);
        if (active) {
          if (row != cur) {
            if (cur >= 0) FLUSH4();
            cur = row; a0 = v0; a1 = v1; a2 = v2; a3 = v3; nrunf = 1.f;
          } else {
            a0 += v0; a1 += v1; a2 += v2; a3 += v3; nrunf += 1.f;
          }
        }
      }
    }
    if (cur >= 0) FLUSH4();
#undef FLUSH4
  }
  __syncthreads();

  // ---- phase 2: pure-bf16 MFMA ----
  int l15 = lane & 15, kg = lane >> 4;
  f32x4 acc = {0.f, 0.f, 0.f, 0.f};

  if constexpr (NCOL == 64) {
    int wm = w >> 2, wn = w & 3;
    int col = wn * 16 + l15;
    for (int ks = 0; ks < 18; ++ks) {
      union { uint4 q; short8v s; } bh, ah;
      bh.q = *(const uint4*)(Bf + (ks * 4 + wn) * 512 + lane * 8);
      if (ks < 16) {
        int rr = ks >> 1;
        int f0 = ((ks & 1) << 5) + (kg << 3);
        int row = ((wm * 16 + l15) << 3) + rr;
        int sw = (row << 6) + (f0 ^ ((l15 & 7) << 3));
        ah.q = *(const uint4*)&agg[sw];
      } else {
        int kb = ((ks - 16) << 5) + (kg << 3);
        ah.q = *(const uint4*)&Xg[(size_t)(d0 + wm * 16 + l15) * 64 + kb];
      }
      acc = __builtin_amdgcn_mfma_f32_16x16x32_bf16(ah.s, bh.s, acc, 0, 0, 0);
    }
    // epilogue: LDS-staged coalesced stores
    __syncthreads();                 // all agg reads done; reuse as stage
#pragma unroll
    for (int i2 = 0; i2 < 4; ++i2) {
      float v = acc[i2] + bias_lds[col];
      if (RELUOUT) v = fmaxf(v, 0.f);
      agg[(wm * 16 + kg * 4 + i2) * 64 + col] = rne_bf16(v);
    }
    __syncthreads();
    {
      int r = t >> 4, c4 = t & 15;
      uint2 v = *(const uint2*)&agg[r * 64 + c4 * 4];
      ((uint2*)OutP)[(size_t)(d0 + r) * 16 + c4] = v;
    }
  } else {
    int wm = w >> 2, wn = (w >> 1) & 1, ksp = w & 1;
    int col = wn * 16 + l15;
    for (int ks = ksp; ks < 18; ks += 2) {
      union { uint4 q; short8v s; } bh, ah;
      bh.q = *(const uint4*)(Bf + (ks * 2 + wn) * 512 + lane * 8);
      if (ks < 16) {
        int rr = ks >> 1;
        int f0 = ((ks & 1) << 5) + (kg << 3);
        int row = ((wm * 16 + l15) << 3) + rr;
        int sw = (row << 6) + (f0 ^ ((l15 & 7) << 3));
        ah.q = *(const uint4*)&agg[sw];
      } else {
        int kb = ((ks - 16) << 5) + (kg << 3);
        ah.q = *(const uint4*)&Xg[(size_t)(d0 + wm * 16 + l15) * 64 + kb];
      }
      acc = __builtin_amdgcn_mfma_f32_16x16x32_bf16(ah.s, bh.s, acc, 0, 0, 0);
    }
    __syncthreads();               // agg reads done before reuse
    float* red = (float*)agg;
    int rbase = wm * 16 + kg * 4;
    if (ksp == 1) {
#pragma unroll
      for (int i2 = 0; i2 < 4; ++i2) red[(rbase + i2) * 36 + col] = acc[i2];
    }
    __syncthreads();
    if (ksp == 0) {
#pragma unroll
      for (int i2 = 0; i2 < 4; ++i2) {
        float v = acc[i2] + red[(rbase + i2) * 36 + col] + bias_lds[col];
        if (RELUOUT) v = fmaxf(v, 0.f);
        ((float*)OutP)[(size_t)(d0 + rbase + i2) * 32 + col] = v;
      }
    }
  }
}

// ---------------- launch ----------------

extern "C" void kernel_launch(void* const* d_in, const int* in_sizes, int n_in,
                              void* d_out, int out_size, void* d_ws, size_t ws_size,
                              hipStream_t stream) {
  const float* x = (const float*)d_in[0];
  const int* ei = (const int*)d_in[1];
  const int* et = (const int*)d_in[2];
  const float* w1 = (const float*)d_in[3];
  const float* r1 = (const float*)d_in[4];
  const float* b1 = (const float*)d_in[5];
  const float* w2 = (const float*)d_in[6];
  const float* r2 = (const float*)d_in[7];
  const float* b2 = (const float*)d_in[8];
  float* out = (float*)d_out;

  int* cnt = (int*)d_ws;                     // NROWS_PAD ints
  int* bsum = cnt + NROWS_PAD;               // 1024
  int* bpre = bsum + 1024;                   // 1024
  int* rowoff = bpre + 1024;                 // NROWS+1 (pad 16)
  int* er = rowoff + NROWS + 16;             // N_EDGES (edge rank)
  int* ep = er + N_EDGES;                    // N_EDGES
  ushort* bf1 = (ushort*)(ep + N_EDGES);     // 36864 (single plane)
  ushort* bf2 = bf1 + 36864;                 // 18432
  ushort* xbf = bf2 + 18432;                 // 12,800,000 (25.6 MB)
  ushort* hbf = xbf + 12800000;              // 12,800,000 (25.6 MB)

  hipMemsetAsync(cnt, 0, (size_t)NROWS_PAD * 4, stream);
  k_setup<<<NB_COUNT + NB_XCAST + NB_PREP1 + NB_PREP2, 256, 0, stream>>>(
      ei, et, cnt, er, x, xbf, w1, r1, bf1, w2, r2, bf2);
  k_bsum<<<NSCAN, 256, 0, stream>>>(cnt, bsum);
  k_scan1<<<1, 1024, 0, stream>>>(bsum, bpre, rowoff);
  k_apply<<<NSCAN, 256, 0, stream>>>(cnt, bpre, rowoff);
  k_scatter<<<(N_EDGES + 255) / 256, 256, 0, stream>>>(ei, et, rowoff, er, ep);

  k_rgcn<64, true, true><<<NBUCK, 512, 0, stream>>>(xbf, bf1, b1, rowoff, ep, hbf);
  k_rgcn<32, false, false><<<NBUCK, 512, 0, stream>>>(hbf, bf2, b2, rowoff, ep, out);
}